// Round 2
// baseline (64.368 us; speedup 1.0000x reference)
//
#include <hip/hip_runtime.h>
#include <math.h>

#define Bb 4
#define Mm 8192
#define Kk 64
#define Cc 32
#define Nn 64
#define Pp 28

#define OFF_PSDF  (Bb*Mm)                          // 32768
#define OFF_INTER (Bb*Mm + Bb*Mm*Kk)               // 2129920
#define OFF_SD    (Bb*Mm + Bb*Mm*Kk + Bb*Mm*Cc)    // 3178496

struct Rad12 { float v[12]; };

// ---------------- Kernel 0: expand curves + params into workspace ----------
// thread g -> k = g&63 (fastest, coalesced), n = (g>>6)&63, b = g>>12
__global__ __launch_bounds__(256)
void curve_prep(const float* __restrict__ pp, Rad12 rad,
                float2* __restrict__ curve_ws, float* __restrict__ params_ws)
{
    const int g = blockIdx.x * 256 + threadIdx.x;   // 16384 threads
    const int k = g & 63;
    const int n = (g >> 6) & 63;
    const int b = g >> 12;

#define PP(p) pp[((b * Pp) + (p)) * Kk + k]

    const int s  = n >> 4;
    const int it = n & 15;
    const float t = (float)it * 0.0625f;            // exact i/16
    const int s1 = (s + 1) & 3;

    float r0 = fabsf(PP(8 + 3 * s + 0));
    float r1 = fabsf(PP(8 + 3 * s + 1));
    float r2 = fabsf(PP(8 + 3 * s + 2));
    float r3 = fabsf(PP(8 + 3 * s1 + 0));
    float w1 = fabsf(PP(20 + 2 * s + 0));
    float w2 = fabsf(PP(20 + 2 * s + 1));

    float a0 = rad.v[3 * s + 0], a1 = rad.v[3 * s + 1];
    float a2 = rad.v[3 * s + 2], a3 = rad.v[3 * s1 + 0];

    float P0x = cosf(a0) * r0, P0y = sinf(a0) * r0;
    float P1x = cosf(a1) * r1, P1y = sinf(a1) * r1;
    float P2x = cosf(a2) * r2, P2y = sinf(a2) * r2;
    float P3x = cosf(a3) * r3, P3y = sinf(a3) * r3;

    float omt = 1.0f - t;
    float b0 = omt * omt * omt;
    float b1 = (3.0f * t) * (omt * omt);
    float b2 = (3.0f * (t * t)) * omt;
    float b3 = t * t * t;
    float bw1 = b1 * w1, bw2 = b2 * w2;
    float den = ((b0 + bw1) + bw2) + b3;
    float nx  = ((b0 * P0x + bw1 * P1x) + bw2 * P2x) + b3 * P3x;
    float ny  = ((b0 * P0y + bw1 * P1y) + bw2 * P2y) + b3 * P3y;

    curve_ws[(b * Nn + n) * Kk + k] = make_float2(nx / den, ny / den);

    if (n < 8) {
        float val;
        if (n < 4) {
            float q0 = PP(0), q1 = PP(1), q2 = PP(2), q3 = PP(3);
            float nrm = sqrtf(q0 * q0 + q1 * q1 + q2 * q2 + q3 * q3);
            val = PP(n) / nrm;
        } else {
            val = PP(n);        // p=4..6 trans, p=7 height
        }
        params_ws[(b * Kk + k) * 8 + n] = val;
    }
#undef PP
}

// ---------------- Kernel 1: main fused kernel ------------------------------
// block = 1024 threads = 16 waves = 16 points (same batch b).
// Phase 1: lane = primitive k. Phase 2: lane = (khalf, c).
__global__ __launch_bounds__(1024)
void csg_main(const float* __restrict__ pts, const float* __restrict__ iw_g,
              const float* __restrict__ uw_g, const int* __restrict__ flag,
              const float2* __restrict__ curve_ws,
              const float* __restrict__ params_ws,
              float* __restrict__ out)
{
    __shared__ __align__(16) float2 s_curve[Nn * Kk];  // [n][k]  32 KB
    __shared__ __align__(16) float2 s_iw[Kk * Cc];     // [k][c] (-40iw, -40(1-iw)) 16 KB
    __shared__ float s_uw[Cc];

    const int tid = threadIdx.x;
    const int bid = blockIdx.x;
    const int b   = bid >> 9;                 // 512 blocks per batch
    const int m0  = (bid & 511) << 4;         // 16 points per block

    // ---- stage LDS ----
    {
        const float4* csrc = (const float4*)(curve_ws + b * (Nn * Kk));
        float4* cdst = (float4*)s_curve;
        cdst[tid]        = csrc[tid];
        cdst[tid + 1024] = csrc[tid + 1024];
        for (int j = tid; j < Kk * Cc; j += 1024) {
            float w = iw_g[b * (Kk * Cc) + j];
            s_iw[j] = make_float2(-40.0f * w, -40.0f * (1.0f - w));
        }
        if (tid < Cc) s_uw[tid] = uw_g[b * Cc + tid];
    }
    __syncthreads();

    const int wid  = tid >> 6;
    const int lane = tid & 63;
    const int m    = m0 + wid;
    const int pt   = b * Mm + m;

    // ================= Phase 1: lane = k =================
    const int k = lane;
    const float* prm = params_ws + ((b << 6) + k) * 8;
    float qw = prm[0], qx = prm[1], qy = prm[2], qz = prm[3];
    float tx = prm[4], ty = prm[5], tz = prm[6], hh = prm[7];

    float px = pts[pt * 3 + 0] - tx;
    float py = pts[pt * 3 + 1] - ty;
    float pz = pts[pt * 3 + 2] - tz;

    float vx = -qx, vy = -qy, vz = -qz;
    float t1x = 2.0f * (vy * pz - vz * py);
    float t1y = 2.0f * (vz * px - vx * pz);
    float t1z = 2.0f * (vx * py - vy * px);
    float c2x = vy * t1z - vz * t1y;
    float c2y = vz * t1x - vx * t1z;
    float c2z = vx * t1y - vy * t1x;
    float plx = px + qw * t1x + c2x;
    float ply = py + qw * t1y + c2y;
    float plz = pz + qw * t1z + c2z;

    float psq = plx * plx + ply * ply;

    float best = 1e30f, bcsq = 0.0f;
#pragma unroll 8
    for (int n = 0; n < Nn; ++n) {
        float2 cv  = s_curve[n * Kk + k];
        float csq  = cv.x * cv.x + cv.y * cv.y;
        float dot  = plx * cv.x + ply * cv.y;
        float d2   = (psq + csq) - 2.0f * dot;
        if (d2 < best) { best = d2; bcsq = csq; }   // strict-less == argmin-first
    }

    float ud    = sqrtf(fmaxf(best, 0.0f) + 1e-12f);
    float sgn   = (sqrtf(psq) <= sqrtf(bcsq)) ? -1.0f : 1.0f;
    float sdf2d = sgn * ud;
    float dzv   = fabsf(plz) - hh;
    float inner = fminf(fmaxf(sdf2d, dzv), 0.0f);
    float r1m   = fmaxf(sdf2d, 0.0f), r2m = fmaxf(dzv, 0.0f);
    float psdf  = inner + sqrtf(r1m * r1m + r2m * r2m + 1e-12f);

    out[OFF_PSDF + pt * Kk + k] = psdf;
    out[OFF_SD   + pt * Kk + k] = ud;

    float occ = 1.0f / (1.0f + __expf(75.0f * psdf));   // sigmoid(-75*psdf)

    // ================= Phase 2: lane = (khalf, c) =================
    const int training = flag[0];
    const int c       = lane & 31;
    const int kbase   = lane & 32;       // k-half offset (0 or 32)

    float inter;
    if (training) {
        float sw = 0.0f, swp = 0.0f;
        for (int j = 0; j < 32; ++j) {
            float og   = __shfl(occ, kbase + j, 64);
            float2 wv  = s_iw[(kbase + j) * Cc + c];
            float pre40 = fmaf(wv.x, og, wv.y);        // = -40 * pre_i
            float e    = __expf(pre40);                 // in [4e-18, 1): safe
            sw += e;
            swp = fmaf(e, pre40, swp);
        }
        sw  += __shfl_xor(sw, 32, 64);
        swp += __shfl_xor(swp, 32, 64);
        inter = (swp / sw) * (-0.025f);
    } else {
        float mx40 = -1e30f;
        for (int j = 0; j < 32; ++j) {
            float og   = __shfl(occ, kbase + j, 64);
            float2 wv  = s_iw[(kbase + j) * Cc + c];
            float pre40 = fmaf(wv.x, og, wv.y);
            mx40 = fmaxf(mx40, pre40);
        }
        mx40 = fmaxf(mx40, __shfl_xor(mx40, 32, 64));
        inter = mx40 * (-0.025f);                       // min_k pre_i
    }

    if (lane < Cc)
        out[OFF_INTER + pt * Cc + c] = inter;

    float pre_u = s_uw[c] * inter;
    if (training) {
        float e2  = __expf(40.0f * pre_u);              // <= e^40: safe
        float num = e2 * pre_u, den = e2;
#pragma unroll
        for (int msk = 16; msk >= 1; msk >>= 1) {
            num += __shfl_xor(num, msk, 64);
            den += __shfl_xor(den, msk, 64);
        }
        if (lane == 0) out[pt] = num / den;
    } else {
        float mxu = pre_u;
#pragma unroll
        for (int msk = 16; msk >= 1; msk >>= 1)
            mxu = fmaxf(mxu, __shfl_xor(mxu, msk, 64));
        if (lane == 0) out[pt] = mxu;
    }
}

// ---------------- host launch ----------------------------------------------
extern "C" void kernel_launch(void* const* d_in, const int* in_sizes, int n_in,
                              void* d_out, int out_size, void* d_ws, size_t ws_size,
                              hipStream_t stream)
{
    const float* pts  = (const float*)d_in[0];
    const float* pp   = (const float*)d_in[1];
    const float* iw   = (const float*)d_in[2];
    const float* uw   = (const float*)d_in[3];
    const int*   flag = (const int*)d_in[4];
    float* out = (float*)d_out;

    float2* curve_ws  = (float2*)d_ws;                                   // 128 KB
    float*  params_ws = (float*)((char*)d_ws + (size_t)Bb * Nn * Kk * sizeof(float2)); // 8 KB

    // control radians with host libm (matches CPython math module)
    Rad12 rad;
    const double th = M_PI * 2.0 / 16.0 + atan(tan(2.0 * M_PI / 16.0) / 3.0);
    for (int i = 0; i < 4; ++i) {
        double base = 2.0 * M_PI / 4.0 * (double)i;
        rad.v[3 * i + 0] = (float)base;
        rad.v[3 * i + 1] = (float)(base + th);
        rad.v[3 * i + 2] = (float)(2.0 * M_PI / 4.0 * (double)(i + 1) - th);
    }

    curve_prep<<<64, 256, 0, stream>>>(pp, rad, curve_ws, params_ws);
    csg_main<<<Bb * Mm / 16, 1024, 0, stream>>>(pts, iw, uw, flag,
                                                curve_ws, params_ws, out);
}

// Round 3
// 46.388 us; speedup vs baseline: 1.3876x; 1.3876x over previous
//
#include <hip/hip_runtime.h>
#include <math.h>

#define Bb 4
#define Mm 8192
#define Kk 64
#define Cc 32
#define Nn 64
#define Pp 28

#define OFF_PSDF  (Bb*Mm)                          // 32768
#define OFF_INTER (Bb*Mm + Bb*Mm*Kk)               // 2129920
#define OFF_SD    (Bb*Mm + Bb*Mm*Kk + Bb*Mm*Cc)    // 3178496

#define W40    57.707801635558535f    // 40*log2(e)
#define NL2_40 (-0.017328679513998632f) // -ln2/40
#define S75    108.20212806667225f    // 75*log2(e)

struct Rad12 { float v[12]; };

__device__ __forceinline__ float fexp2(float x){ return __builtin_amdgcn_exp2f(x); }
__device__ __forceinline__ float frcp(float x){ return __builtin_amdgcn_rcpf(x); }
__device__ __forceinline__ float bperm(int idx4, float v){
    return __int_as_float(__builtin_amdgcn_ds_bpermute(idx4, __float_as_int(v)));
}

// ---------------- Kernel 0: expand curves + params into workspace ----------
// thread g -> k = g&63 (coalesced), n = (g>>6)&63, b = g>>12
__global__ __launch_bounds__(256)
void curve_prep(const float* __restrict__ pp, Rad12 rad,
                float2* __restrict__ m2c_ws, float2* __restrict__ csqp_ws,
                float* __restrict__ params_ws)
{
    const int g = blockIdx.x * 256 + threadIdx.x;   // 16384 threads
    const int k = g & 63;
    const int n = (g >> 6) & 63;
    const int b = g >> 12;

#define PP(p) pp[((b * Pp) + (p)) * Kk + k]

    const int s  = n >> 4;
    const int it = n & 15;
    const float t = (float)it * 0.0625f;            // exact i/16
    const int s1 = (s + 1) & 3;

    float r0 = fabsf(PP(8 + 3 * s + 0));
    float r1 = fabsf(PP(8 + 3 * s + 1));
    float r2 = fabsf(PP(8 + 3 * s + 2));
    float r3 = fabsf(PP(8 + 3 * s1 + 0));
    float w1 = fabsf(PP(20 + 2 * s + 0));
    float w2 = fabsf(PP(20 + 2 * s + 1));

    float a0 = rad.v[3 * s + 0], a1 = rad.v[3 * s + 1];
    float a2 = rad.v[3 * s + 2], a3 = rad.v[3 * s1 + 0];

    float P0x = cosf(a0) * r0, P0y = sinf(a0) * r0;
    float P1x = cosf(a1) * r1, P1y = sinf(a1) * r1;
    float P2x = cosf(a2) * r2, P2y = sinf(a2) * r2;
    float P3x = cosf(a3) * r3, P3y = sinf(a3) * r3;

    float omt = 1.0f - t;
    float b0 = omt * omt * omt;
    float b1 = (3.0f * t) * (omt * omt);
    float b2 = (3.0f * (t * t)) * omt;
    float b3 = t * t * t;
    float bw1 = b1 * w1, bw2 = b2 * w2;
    float den = ((b0 + bw1) + bw2) + b3;
    float nx  = ((b0 * P0x + bw1 * P1x) + bw2 * P2x) + b3 * P3x;
    float ny  = ((b0 * P0y + bw1 * P1y) + bw2 * P2y) + b3 * P3y;

    float cx = nx / den, cy = ny / den;
    m2c_ws[(b * Nn + n) * Kk + k] = make_float2(-2.0f * cx, -2.0f * cy);
    float csq = cx * cx + cy * cy;
    ((float*)csqp_ws)[((b * (Nn/2) + (n >> 1)) * Kk + k) * 2 + (n & 1)] = csq;

    if (n < 8) {
        float val;
        if (n < 4) {
            float q0 = PP(0), q1 = PP(1), q2 = PP(2), q3 = PP(3);
            float nrm = sqrtf(q0 * q0 + q1 * q1 + q2 * q2 + q3 * q3);
            val = PP(n) / nrm;
        } else {
            val = PP(n);        // p=4..6 trans, p=7 height
        }
        params_ws[(b * Kk + k) * 8 + n] = val;
    }
#undef PP
}

// ---------------- Kernel 1: main fused kernel ------------------------------
// block = 1024 threads = 16 waves; each wave = 4 points (lane = primitive k).
__global__ __launch_bounds__(1024, 8)
void csg_main(const float* __restrict__ pts, const float* __restrict__ iw_g,
              const float* __restrict__ uw_g, const int* __restrict__ flag,
              const float2* __restrict__ m2c_ws, const float2* __restrict__ csqp_ws,
              const float* __restrict__ params_ws, float* __restrict__ out)
{
    __shared__ __align__(16) float2 s_m2c[Nn * Kk];       // [n][k]  32 KB
    __shared__ __align__(16) float2 s_csqp[(Nn/2) * Kk];  // [n2][k] 16 KB
    __shared__ __align__(16) float2 s_iw[Kk * Cc];        // [k][c]  16 KB

    const int tid = threadIdx.x;
    const int bid = blockIdx.x;
    const int b   = bid >> 7;                  // 128 blocks per batch
    const int m0  = (bid & 127) << 6;          // 64 points per block

    // ---- stage LDS ----
    {
        const float4* s1 = (const float4*)(m2c_ws + (size_t)b * Nn * Kk);
        float4* d1 = (float4*)s_m2c;
        d1[tid]        = s1[tid];
        d1[tid + 1024] = s1[tid + 1024];
        const float4* s2 = (const float4*)(csqp_ws + (size_t)b * (Nn/2) * Kk);
        ((float4*)s_csqp)[tid] = s2[tid];
        float w0 = iw_g[b * (Kk * Cc) + tid];
        float w1 = iw_g[b * (Kk * Cc) + tid + 1024];
        s_iw[tid]        = make_float2(w0 * (-W40), (w0 - 1.0f) * W40);
        s_iw[tid + 1024] = make_float2(w1 * (-W40), (w1 - 1.0f) * W40);
    }
    __syncthreads();

    const int wid  = tid >> 6;
    const int lane = tid & 63;
    const int pt0  = b * Mm + m0 + (wid << 2);

    // ================= Phase 1: lane = k, 4 points =================
    const int k = lane;
    const float4* prm4 = (const float4*)(params_ws + ((b << 6) + k) * 8);
    float4 q4 = prm4[0];   // qw qx qy qz (normalized)
    float4 t4 = prm4[1];   // tx ty tz height

    const float4* pts4 = (const float4*)(pts + (size_t)pt0 * 3);
    float4 A = pts4[0], Bv = pts4[1], Cv = pts4[2];
    float pxs[4] = {A.x, A.w, Bv.z, Cv.y};
    float pys[4] = {A.y, Bv.x, Bv.w, Cv.z};
    float pzs[4] = {A.z, Bv.y, Cv.x, Cv.w};

    float plx[4], ply[4], plzv[4], psq[4];
    float vx = -q4.y, vy = -q4.z, vz = -q4.w, qw = q4.x;
#pragma unroll
    for (int p = 0; p < 4; ++p) {
        float px = pxs[p] - t4.x, py = pys[p] - t4.y, pz = pzs[p] - t4.z;
        float t1x = 2.0f * (vy * pz - vz * py);
        float t1y = 2.0f * (vz * px - vx * pz);
        float t1z = 2.0f * (vx * py - vy * px);
        plx[p]  = px + qw * t1x + (vy * t1z - vz * t1y);
        ply[p]  = py + qw * t1y + (vz * t1x - vx * t1z);
        plzv[p] = pz + qw * t1z + (vx * t1y - vy * t1x);
        psq[p]  = plx[p] * plx[p] + ply[p] * ply[p];
    }

    float bval[4] = {1e30f, 1e30f, 1e30f, 1e30f};
    float bcsq[4] = {0.0f, 0.0f, 0.0f, 0.0f};
#pragma unroll 8
    for (int n2 = 0; n2 < Nn / 2; ++n2) {
        float2 ca = s_m2c[(2 * n2) * Kk + k];
        float2 cb = s_m2c[(2 * n2 + 1) * Kk + k];
        float2 cq = s_csqp[n2 * Kk + k];
#pragma unroll
        for (int p = 0; p < 4; ++p) {
            float da = psq[p] + fmaf(ca.x, plx[p], fmaf(ca.y, ply[p], cq.x));
            if (da < bval[p]) { bval[p] = da; bcsq[p] = cq.x; }   // strict < == argmin-first
            float db = psq[p] + fmaf(cb.x, plx[p], fmaf(cb.y, ply[p], cq.y));
            if (db < bval[p]) { bval[p] = db; bcsq[p] = cq.y; }
        }
    }

    float occ[4];
#pragma unroll
    for (int p = 0; p < 4; ++p) {
        float ud    = sqrtf(fmaxf(bval[p], 0.0f) + 1e-12f);
        float sgn   = (sqrtf(psq[p]) <= sqrtf(bcsq[p])) ? -1.0f : 1.0f;
        float sdf2d = sgn * ud;
        float dzv   = fabsf(plzv[p]) - t4.w;
        float inner = fminf(fmaxf(sdf2d, dzv), 0.0f);
        float r1m   = fmaxf(sdf2d, 0.0f), r2m = fmaxf(dzv, 0.0f);
        float psdf  = inner + sqrtf(r1m * r1m + r2m * r2m + 1e-12f);
        out[OFF_PSDF + (pt0 + p) * Kk + k] = psdf;
        out[OFF_SD   + (pt0 + p) * Kk + k] = ud;
        occ[p] = frcp(1.0f + fexp2(S75 * psdf));   // sigmoid(-75*psdf)
    }

    // ================= Phase 2: lane = (khalf, c) =================
    const int training = flag[0];
    const int c    = lane & 31;
    const int kb   = lane & 32;
    const int idxb = kb << 2;                       // bpermute byte base
    const float2* iwp = s_iw + kb * Cc + c;         // row advance: j*Cc

    float inter[4];
    if (training) {
        float sw[4]  = {0, 0, 0, 0};
        float swp[4] = {0, 0, 0, 0};
#pragma unroll
        for (int j = 0; j < 32; ++j) {
            int i4 = idxb + (j << 2);
            float2 wv = iwp[j * Cc];
#pragma unroll
            for (int p = 0; p < 4; ++p) {
                float o   = bperm(i4, occ[p]);
                float pre = fmaf(wv.x, o, wv.y);    // = -40*log2e * pre_i
                float e   = fexp2(pre);             // in (0,1]: safe
                sw[p]  += e;
                swp[p]  = fmaf(e, pre, swp[p]);
            }
        }
#pragma unroll
        for (int p = 0; p < 4; ++p) {
            float swt  = sw[p]  + __shfl_xor(sw[p], 32, 64);
            float swpt = swp[p] + __shfl_xor(swp[p], 32, 64);
            inter[p] = swpt * frcp(swt) * NL2_40;
        }
    } else {
        float mx[4] = {-1e30f, -1e30f, -1e30f, -1e30f};
#pragma unroll
        for (int j = 0; j < 32; ++j) {
            int i4 = idxb + (j << 2);
            float2 wv = iwp[j * Cc];
#pragma unroll
            for (int p = 0; p < 4; ++p) {
                float o   = bperm(i4, occ[p]);
                float pre = fmaf(wv.x, o, wv.y);
                mx[p] = fmaxf(mx[p], pre);
            }
        }
#pragma unroll
        for (int p = 0; p < 4; ++p) {
            float m2 = fmaxf(mx[p], __shfl_xor(mx[p], 32, 64));
            inter[p] = m2 * NL2_40;                 // min_k pre_i
        }
    }

    if (lane < Cc) {
#pragma unroll
        for (int p = 0; p < 4; ++p)
            out[OFF_INTER + (pt0 + p) * Cc + c] = inter[p];
    }

    // ---- union over c (softmax / max) ----
    float uwv = uw_g[b * Cc + c];
    float resv[4];
    if (training) {
#pragma unroll
        for (int p = 0; p < 4; ++p) {
            float pu  = uwv * inter[p];
            float e   = fexp2(W40 * pu);            // exp(40*pre_u), <= e^40: safe
            float num = e * pu, den = e;
#pragma unroll
            for (int msk = 16; msk >= 1; msk >>= 1) {
                num += __shfl_xor(num, msk, 64);
                den += __shfl_xor(den, msk, 64);
            }
            resv[p] = num * frcp(den);
        }
    } else {
#pragma unroll
        for (int p = 0; p < 4; ++p) {
            float pu = uwv * inter[p];
#pragma unroll
            for (int msk = 16; msk >= 1; msk >>= 1)
                pu = fmaxf(pu, __shfl_xor(pu, msk, 64));
            resv[p] = pu;
        }
    }
    if (lane == 0)
        *(float4*)(out + pt0) = make_float4(resv[0], resv[1], resv[2], resv[3]);
}

// ---------------- host launch ----------------------------------------------
extern "C" void kernel_launch(void* const* d_in, const int* in_sizes, int n_in,
                              void* d_out, int out_size, void* d_ws, size_t ws_size,
                              hipStream_t stream)
{
    const float* pts  = (const float*)d_in[0];
    const float* pp   = (const float*)d_in[1];
    const float* iw   = (const float*)d_in[2];
    const float* uw   = (const float*)d_in[3];
    const int*   flag = (const int*)d_in[4];
    float* out = (float*)d_out;

    float2* m2c_ws  = (float2*)d_ws;                                        // 128 KB
    float2* csqp_ws = (float2*)((char*)d_ws + (size_t)Bb*Nn*Kk*sizeof(float2));      // 64 KB
    float*  params_ws = (float*)((char*)d_ws + (size_t)Bb*Nn*Kk*sizeof(float2)
                                             + (size_t)Bb*(Nn/2)*Kk*sizeof(float2)); // 8 KB

    // control radians with host libm (matches CPython math module)
    Rad12 rad;
    const double th = M_PI * 2.0 / 16.0 + atan(tan(2.0 * M_PI / 16.0) / 3.0);
    for (int i = 0; i < 4; ++i) {
        double base = 2.0 * M_PI / 4.0 * (double)i;
        rad.v[3 * i + 0] = (float)base;
        rad.v[3 * i + 1] = (float)(base + th);
        rad.v[3 * i + 2] = (float)(2.0 * M_PI / 4.0 * (double)(i + 1) - th);
    }

    curve_prep<<<64, 256, 0, stream>>>(pp, rad, m2c_ws, csqp_ws, params_ws);
    csg_main<<<Bb * Mm / 64, 1024, 0, stream>>>(pts, iw, uw, flag,
                                                m2c_ws, csqp_ws, params_ws, out);
}

// Round 4
// 45.361 us; speedup vs baseline: 1.4190x; 1.0226x over previous
//
#include <hip/hip_runtime.h>
#include <math.h>

#define Bb 4
#define Mm 8192
#define Kk 64
#define Cc 32
#define Nn 64
#define Pp 28

#define OFF_PSDF  (Bb*Mm)                          // 32768
#define OFF_INTER (Bb*Mm + Bb*Mm*Kk)               // 2129920
#define OFF_SD    (Bb*Mm + Bb*Mm*Kk + Bb*Mm*Cc)    // 3178496

#define W40    57.707801635558535f      // 40*log2(e)
#define NL2_40 (-0.017328679513998632f) // -ln2/40
#define S75    108.20212806667225f      // 75*log2(e)

typedef float f32x2 __attribute__((ext_vector_type(2)));

struct Rad12 { float v[12]; };

__device__ __forceinline__ float fexp2(float x){ return __builtin_amdgcn_exp2f(x); }
__device__ __forceinline__ float frcp(float x){ return __builtin_amdgcn_rcpf(x); }
__device__ __forceinline__ f32x2 pk_fma(f32x2 a, f32x2 b, f32x2 c){
    f32x2 d;
    asm("v_pk_fma_f32 %0, %1, %2, %3" : "=v"(d) : "v"(a), "v"(b), "v"(c));
    return d;
}

// ---------------- Kernel 0: expand curves + params into workspace ----------
// thread g -> k = g&63 (coalesced), n = (g>>6)&63, b = g>>12
// Outputs: split arrays [b][j=n>>1][k][h=n&1]: cx(-2x), cy(-2y), cq(csq); params.
__global__ __launch_bounds__(256)
void curve_prep(const float* __restrict__ pp, Rad12 rad,
                float* __restrict__ ws_cx, float* __restrict__ ws_cy,
                float* __restrict__ ws_cq, float* __restrict__ params_ws)
{
    const int g = blockIdx.x * 256 + threadIdx.x;   // 16384 threads
    const int k = g & 63;
    const int n = (g >> 6) & 63;
    const int b = g >> 12;

#define PP(p) pp[((b * Pp) + (p)) * Kk + k]

    const int s  = n >> 4;
    const int it = n & 15;
    const float t = (float)it * 0.0625f;            // exact i/16
    const int s1 = (s + 1) & 3;

    float r0 = fabsf(PP(8 + 3 * s + 0));
    float r1 = fabsf(PP(8 + 3 * s + 1));
    float r2 = fabsf(PP(8 + 3 * s + 2));
    float r3 = fabsf(PP(8 + 3 * s1 + 0));
    float w1 = fabsf(PP(20 + 2 * s + 0));
    float w2 = fabsf(PP(20 + 2 * s + 1));

    float a0 = rad.v[3 * s + 0], a1 = rad.v[3 * s + 1];
    float a2 = rad.v[3 * s + 2], a3 = rad.v[3 * s1 + 0];

    float P0x = cosf(a0) * r0, P0y = sinf(a0) * r0;
    float P1x = cosf(a1) * r1, P1y = sinf(a1) * r1;
    float P2x = cosf(a2) * r2, P2y = sinf(a2) * r2;
    float P3x = cosf(a3) * r3, P3y = sinf(a3) * r3;

    float omt = 1.0f - t;
    float b0 = omt * omt * omt;
    float b1 = (3.0f * t) * (omt * omt);
    float b2 = (3.0f * (t * t)) * omt;
    float b3 = t * t * t;
    float bw1 = b1 * w1, bw2 = b2 * w2;
    float den = ((b0 + bw1) + bw2) + b3;
    float nx  = ((b0 * P0x + bw1 * P1x) + bw2 * P2x) + b3 * P3x;
    float ny  = ((b0 * P0y + bw1 * P1y) + bw2 * P2y) + b3 * P3y;

    float cx = nx / den, cy = ny / den;
    const int idx = ((b * 32 + (n >> 1)) * 64 + k) * 2 + (n & 1);
    ws_cx[idx] = -2.0f * cx;
    ws_cy[idx] = -2.0f * cy;
    ws_cq[idx] = cx * cx + cy * cy;

    if (n < 8) {
        float val;
        if (n < 4) {
            float q0 = PP(0), q1 = PP(1), q2 = PP(2), q3 = PP(3);
            float nrm = sqrtf(q0 * q0 + q1 * q1 + q2 * q2 + q3 * q3);
            val = PP(n) / nrm;
        } else {
            val = PP(n);        // p=4..6 trans, p=7 height
        }
        params_ws[(b * Kk + k) * 8 + n] = val;
    }
#undef PP
}

// ---------------- Kernel 1: main fused kernel ------------------------------
// block = 1024 threads = 16 waves; each wave = 4 points (lane = primitive k).
// LDS pool (floats): [0,4096) cx pairs | [4096,8192) cy pairs |
//                    [8192,12288) cq pairs (aliased by occ after barrier) |
//                    [12288,16384) iw pre-scaled pairs.
__global__ __launch_bounds__(1024, 8)
void csg_main(const float* __restrict__ pts, const float* __restrict__ iw_g,
              const float* __restrict__ uw_g, const int* __restrict__ flag,
              const float* __restrict__ ws_cx, const float* __restrict__ ws_cy,
              const float* __restrict__ ws_cq, const float* __restrict__ params_ws,
              float* __restrict__ out)
{
    __shared__ __align__(16) float s_pool[16384];   // 64 KB

    const int tid = threadIdx.x;
    const int bid = blockIdx.x;
    const int b   = bid >> 7;                  // 128 blocks per batch
    const int m0  = (bid & 127) << 6;          // 64 points per block

    // ---- stage LDS ----
    {
        ((float4*)&s_pool[0])[tid]     = ((const float4*)(ws_cx + b * 4096))[tid];
        ((float4*)&s_pool[4096])[tid]  = ((const float4*)(ws_cy + b * 4096))[tid];
        ((float4*)&s_pool[8192])[tid]  = ((const float4*)(ws_cq + b * 4096))[tid];
        float w0 = iw_g[b * 2048 + tid];
        float w1 = iw_g[b * 2048 + tid + 1024];
        s_pool[12288 + tid * 2]        = w0 * (-W40);
        s_pool[12288 + tid * 2 + 1]    = (w0 - 1.0f) * W40;
        s_pool[14336 + tid * 2]        = w1 * (-W40);
        s_pool[14336 + tid * 2 + 1]    = (w1 - 1.0f) * W40;
    }
    __syncthreads();

    const int wid  = tid >> 6;
    const int lane = tid & 63;
    const int pt0  = b * Mm + m0 + (wid << 2);

    // ================= Phase 1: lane = k, 4 points =================
    const int k = lane;
    const float4* prm4 = (const float4*)(params_ws + ((b << 6) + k) * 8);
    float4 q4 = prm4[0];   // qw qx qy qz (normalized)
    float4 t4 = prm4[1];   // tx ty tz height

    const float4* pts4 = (const float4*)(pts + (size_t)pt0 * 3);
    float4 A = pts4[0], Bv = pts4[1], Cv = pts4[2];
    float pxs[4] = {A.x, A.w, Bv.z, Cv.y};
    float pys[4] = {A.y, Bv.x, Bv.w, Cv.z};
    float pzs[4] = {A.z, Bv.y, Cv.x, Cv.w};

    f32x2 plx2[4], ply2[4];
    float plzv[4], psq[4];
    float vx = -q4.y, vy = -q4.z, vz = -q4.w, qw = q4.x;
#pragma unroll
    for (int p = 0; p < 4; ++p) {
        float px = pxs[p] - t4.x, py = pys[p] - t4.y, pz = pzs[p] - t4.z;
        float t1x = 2.0f * (vy * pz - vz * py);
        float t1y = 2.0f * (vz * px - vx * pz);
        float t1z = 2.0f * (vx * py - vy * px);
        float plx = px + qw * t1x + (vy * t1z - vz * t1y);
        float ply = py + qw * t1y + (vz * t1x - vx * t1z);
        plzv[p]   = pz + qw * t1z + (vx * t1y - vy * t1x);
        psq[p]    = plx * plx + ply * ply;
        plx2[p].x = plx; plx2[p].y = plx;
        ply2[p].x = ply; ply2[p].y = ply;
    }

    // keyless exact tracking: best = min_n (csq - 2*dot)  (psq added at end —
    // strict-< argmin & final d2 bit-identical to per-sample psq+... version)
    float best[4] = {1e30f, 1e30f, 1e30f, 1e30f};
    float bcsq[4] = {0.0f, 0.0f, 0.0f, 0.0f};
    const f32x2* cxp = (const f32x2*)&s_pool[k * 2];
    const f32x2* cyp = (const f32x2*)&s_pool[4096 + k * 2];
    const f32x2* cqp = (const f32x2*)&s_pool[8192 + k * 2];
#pragma unroll
    for (int j = 0; j < 32; ++j) {
        f32x2 cx2 = cxp[j * 64];         // offsets are j*512B immediates
        f32x2 cy2 = cyp[j * 64];
        f32x2 cq2 = cqp[j * 64];
#pragma unroll
        for (int p = 0; p < 4; ++p) {
            f32x2 d = pk_fma(cx2, plx2[p], pk_fma(cy2, ply2[p], cq2));
            if (d.x < best[p]) { best[p] = d.x; bcsq[p] = cq2.x; }
            if (d.y < best[p]) { best[p] = d.y; bcsq[p] = cq2.y; }
        }
    }

    float occ[4];
#pragma unroll
    for (int p = 0; p < 4; ++p) {
        float d2    = psq[p] + best[p];
        float ud    = sqrtf(fmaxf(d2, 0.0f) + 1e-12f);
        float sgn   = (sqrtf(psq[p]) <= sqrtf(bcsq[p])) ? -1.0f : 1.0f;
        float sdf2d = sgn * ud;
        float dzv   = fabsf(plzv[p]) - t4.w;
        float inner = fminf(fmaxf(sdf2d, dzv), 0.0f);
        float r1m   = fmaxf(sdf2d, 0.0f), r2m = fmaxf(dzv, 0.0f);
        float psdf  = inner + sqrtf(r1m * r1m + r2m * r2m + 1e-12f);
        out[OFF_PSDF + (pt0 + p) * Kk + k] = psdf;
        out[OFF_SD   + (pt0 + p) * Kk + k] = ud;
        occ[p] = frcp(1.0f + fexp2(S75 * psdf));   // sigmoid(-75*psdf)
    }

    // ---- barrier: everyone done reading cq region; alias it with occ ----
    __syncthreads();
    *(float4*)&s_pool[8192 + tid * 4] = make_float4(occ[0], occ[1], occ[2], occ[3]);

    // ================= Phase 2: lane = (khalf, c) =================
    const int training = flag[0];
    const int c    = lane & 31;
    const int kb   = lane & 32;
    const float4* occp = (const float4*)&s_pool[8192 + ((wid << 6) + kb) * 4]; // [j]
    const f32x2*  iwp  = (const f32x2*)&s_pool[12288 + ((kb << 5) + c) * 2];   // [j*32]

    float inter[4];
    if (training) {
        float sw[4]  = {0, 0, 0, 0};
        float swp[4] = {0, 0, 0, 0};
#pragma unroll
        for (int j = 0; j < 32; ++j) {
            float4 o4 = occp[j];
            f32x2 wv  = iwp[j * 32];
            float os[4] = {o4.x, o4.y, o4.z, o4.w};
#pragma unroll
            for (int p = 0; p < 4; ++p) {
                float pre = fmaf(wv.x, os[p], wv.y);   // = -40*log2e * pre_i
                float e   = fexp2(pre);                 // in (0,1]: safe
                sw[p]  += e;
                swp[p]  = fmaf(e, pre, swp[p]);
            }
        }
#pragma unroll
        for (int p = 0; p < 4; ++p) {
            float swt  = sw[p]  + __shfl_xor(sw[p], 32, 64);
            float swpt = swp[p] + __shfl_xor(swp[p], 32, 64);
            inter[p] = swpt * frcp(swt) * NL2_40;
        }
    } else {
        float mx[4] = {-1e30f, -1e30f, -1e30f, -1e30f};
#pragma unroll
        for (int j = 0; j < 32; ++j) {
            float4 o4 = occp[j];
            f32x2 wv  = iwp[j * 32];
            float os[4] = {o4.x, o4.y, o4.z, o4.w};
#pragma unroll
            for (int p = 0; p < 4; ++p)
                mx[p] = fmaxf(mx[p], fmaf(wv.x, os[p], wv.y));
        }
#pragma unroll
        for (int p = 0; p < 4; ++p) {
            float m2 = fmaxf(mx[p], __shfl_xor(mx[p], 32, 64));
            inter[p] = m2 * NL2_40;                 // min_k pre_i
        }
    }

    if (lane < Cc) {
#pragma unroll
        for (int p = 0; p < 4; ++p)
            out[OFF_INTER + (pt0 + p) * Cc + c] = inter[p];
    }

    // ---- union over c (softmax / max) ----
    float uwv = uw_g[b * Cc + c];
    float resv[4];
    if (training) {
#pragma unroll
        for (int p = 0; p < 4; ++p) {
            float pu  = uwv * inter[p];
            float e   = fexp2(W40 * pu);            // exp(40*pre_u), <= e^40: safe
            float num = e * pu, den = e;
#pragma unroll
            for (int msk = 16; msk >= 1; msk >>= 1) {
                num += __shfl_xor(num, msk, 64);
                den += __shfl_xor(den, msk, 64);
            }
            resv[p] = num * frcp(den);
        }
    } else {
#pragma unroll
        for (int p = 0; p < 4; ++p) {
            float pu = uwv * inter[p];
#pragma unroll
            for (int msk = 16; msk >= 1; msk >>= 1)
                pu = fmaxf(pu, __shfl_xor(pu, msk, 64));
            resv[p] = pu;
        }
    }
    if (lane == 0)
        *(float4*)(out + pt0) = make_float4(resv[0], resv[1], resv[2], resv[3]);
}

// ---------------- host launch ----------------------------------------------
extern "C" void kernel_launch(void* const* d_in, const int* in_sizes, int n_in,
                              void* d_out, int out_size, void* d_ws, size_t ws_size,
                              hipStream_t stream)
{
    const float* pts  = (const float*)d_in[0];
    const float* pp   = (const float*)d_in[1];
    const float* iw   = (const float*)d_in[2];
    const float* uw   = (const float*)d_in[3];
    const int*   flag = (const int*)d_in[4];
    float* out = (float*)d_out;

    float* ws_cx = (float*)d_ws;                       // 64 KB (16384 floats)
    float* ws_cy = ws_cx + 16384;                      // 64 KB
    float* ws_cq = ws_cy + 16384;                      // 64 KB
    float* params_ws = ws_cq + 16384;                  // 8 KB

    // control radians with host libm (matches CPython math module)
    Rad12 rad;
    const double th = M_PI * 2.0 / 16.0 + atan(tan(2.0 * M_PI / 16.0) / 3.0);
    for (int i = 0; i < 4; ++i) {
        double base = 2.0 * M_PI / 4.0 * (double)i;
        rad.v[3 * i + 0] = (float)base;
        rad.v[3 * i + 1] = (float)(base + th);
        rad.v[3 * i + 2] = (float)(2.0 * M_PI / 4.0 * (double)(i + 1) - th);
    }

    curve_prep<<<64, 256, 0, stream>>>(pp, rad, ws_cx, ws_cy, ws_cq, params_ws);
    csg_main<<<Bb * Mm / 64, 1024, 0, stream>>>(pts, iw, uw, flag,
                                                ws_cx, ws_cy, ws_cq, params_ws, out);
}

// Round 5
// 45.007 us; speedup vs baseline: 1.4302x; 1.0079x over previous
//
#include <hip/hip_runtime.h>
#include <math.h>

#define Bb 4
#define Mm 8192
#define Kk 64
#define Cc 32
#define Nn 64
#define Pp 28

#define OFF_PSDF  (Bb*Mm)                          // 32768
#define OFF_INTER (Bb*Mm + Bb*Mm*Kk)               // 2129920
#define OFF_SD    (Bb*Mm + Bb*Mm*Kk + Bb*Mm*Cc)    // 3178496

#define W40    57.707801635558535f      // 40*log2(e)
#define NL2_40 (-0.017328679513998632f) // -ln2/40
#define S75    108.20212806667225f      // 75*log2(e)

typedef float f32x2 __attribute__((ext_vector_type(2)));
typedef float f32x4 __attribute__((ext_vector_type(4)));

struct Rad12 { float v[12]; };

__device__ __forceinline__ float fexp2(float x){ return __builtin_amdgcn_exp2f(x); }
__device__ __forceinline__ float frcp(float x){ return __builtin_amdgcn_rcpf(x); }
__device__ __forceinline__ f32x2 pk_fma(f32x2 a, f32x2 b, f32x2 c){
    f32x2 d; asm("v_pk_fma_f32 %0, %1, %2, %3" : "=v"(d) : "v"(a), "v"(b), "v"(c)); return d;
}
__device__ __forceinline__ f32x2 pk_mul(f32x2 a, f32x2 b){
    f32x2 d; asm("v_pk_mul_f32 %0, %1, %2" : "=v"(d) : "v"(a), "v"(b)); return d;
}

// ---------------- Kernel 0: expand curves + params into workspace ----------
// thread g -> k = g&63 (coalesced), n = (g>>6)&63, b = g>>12
// ws_c layout [b][j=n>>1][k][4] = {m2x_even, m2x_odd, m2y_even, m2y_odd}
__global__ __launch_bounds__(256)
void curve_prep(const float* __restrict__ pp, Rad12 rad,
                float* __restrict__ ws_c, float* __restrict__ params_ws)
{
    const int g = blockIdx.x * 256 + threadIdx.x;   // 16384 threads
    const int k = g & 63;
    const int n = (g >> 6) & 63;
    const int b = g >> 12;

#define PP(p) pp[((b * Pp) + (p)) * Kk + k]

    const int s  = n >> 4;
    const int it = n & 15;
    const float t = (float)it * 0.0625f;            // exact i/16
    const int s1 = (s + 1) & 3;

    float r0 = fabsf(PP(8 + 3 * s + 0));
    float r1 = fabsf(PP(8 + 3 * s + 1));
    float r2 = fabsf(PP(8 + 3 * s + 2));
    float r3 = fabsf(PP(8 + 3 * s1 + 0));
    float w1 = fabsf(PP(20 + 2 * s + 0));
    float w2 = fabsf(PP(20 + 2 * s + 1));

    float a0 = rad.v[3 * s + 0], a1 = rad.v[3 * s + 1];
    float a2 = rad.v[3 * s + 2], a3 = rad.v[3 * s1 + 0];

    float P0x = cosf(a0) * r0, P0y = sinf(a0) * r0;
    float P1x = cosf(a1) * r1, P1y = sinf(a1) * r1;
    float P2x = cosf(a2) * r2, P2y = sinf(a2) * r2;
    float P3x = cosf(a3) * r3, P3y = sinf(a3) * r3;

    float omt = 1.0f - t;
    float b0 = omt * omt * omt;
    float b1 = (3.0f * t) * (omt * omt);
    float b2 = (3.0f * (t * t)) * omt;
    float b3 = t * t * t;
    float bw1 = b1 * w1, bw2 = b2 * w2;
    float den = ((b0 + bw1) + bw2) + b3;
    float nx  = ((b0 * P0x + bw1 * P1x) + bw2 * P2x) + b3 * P3x;
    float ny  = ((b0 * P0y + bw1 * P1y) + bw2 * P2y) + b3 * P3y;

    float cx = nx / den, cy = ny / den;
    const int j = n >> 1, h = n & 1;
    float* base = ws_c + (((b * 32 + j) * 64) + k) * 4;
    base[h]     = -2.0f * cx;
    base[2 + h] = -2.0f * cy;

    if (n < 8) {
        float val;
        if (n < 4) {
            float q0 = PP(0), q1 = PP(1), q2 = PP(2), q3 = PP(3);
            float nrm = sqrtf(q0 * q0 + q1 * q1 + q2 * q2 + q3 * q3);
            val = PP(n) / nrm;
        } else {
            val = PP(n);        // p=4..6 trans, p=7 height
        }
        params_ws[(b * Kk + k) * 8 + n] = val;
    }
#undef PP
}

// ---------------- Kernel 1: main fused kernel ------------------------------
// block = 512 threads = 8 waves; each wave = 4 points (lane = primitive k).
// LDS pool (floats): [0, 8192)  curve f32x4 per (j,k)  (aliased by occ in ph2)
//                    [8192,12288) iw pre-scaled pairs [k][c]
__global__ __launch_bounds__(512, 6)
void csg_main(const float* __restrict__ pts, const float* __restrict__ iw_g,
              const float* __restrict__ uw_g, const int* __restrict__ flag,
              const float* __restrict__ ws_c, const float* __restrict__ params_ws,
              float* __restrict__ out)
{
    __shared__ __align__(16) float s_pool[12288];   // 48 KB

    const int tid = threadIdx.x;
    const int bid = blockIdx.x;
    const int b   = bid >> 8;                  // 256 blocks per batch
    const int m0  = (bid & 255) << 5;          // 32 points per block

    // ---- stage LDS ----
    {
        const f32x4* cs = (const f32x4*)(ws_c + (size_t)b * 8192);
        f32x4* cd = (f32x4*)s_pool;
#pragma unroll
        for (int i = 0; i < 4; ++i) cd[tid + i * 512] = cs[tid + i * 512];
#pragma unroll
        for (int i = 0; i < 4; ++i) {
            float w = iw_g[b * 2048 + tid + i * 512];
            ((float2*)&s_pool[8192])[tid + i * 512] =
                make_float2(w * (-W40), (w - 1.0f) * W40);
        }
    }
    __syncthreads();

    const int wid  = tid >> 6;
    const int lane = tid & 63;
    const int pt0  = b * Mm + m0 + (wid << 2);

    // ================= Phase 1: lane = k, 4 points =================
    const int k = lane;
    const float4* prm4 = (const float4*)(params_ws + ((b << 6) + k) * 8);
    float4 q4 = prm4[0];   // qw qx qy qz (normalized)
    float4 t4 = prm4[1];   // tx ty tz height

    const float4* pts4 = (const float4*)(pts + (size_t)pt0 * 3);
    float4 A = pts4[0], Bv = pts4[1], Cv = pts4[2];
    float pxs[4] = {A.x, A.w, Bv.z, Cv.y};
    float pys[4] = {A.y, Bv.x, Bv.w, Cv.z};
    float pzs[4] = {A.z, Bv.y, Cv.x, Cv.w};

    f32x2 plx4[4], ply4[4];          // (4*plx, 4*plx), (4*ply, 4*ply)
    float plzv[4], psq[4];
    float vx = -q4.y, vy = -q4.z, vz = -q4.w, qw = q4.x;
#pragma unroll
    for (int p = 0; p < 4; ++p) {
        float px = pxs[p] - t4.x, py = pys[p] - t4.y, pz = pzs[p] - t4.z;
        float t1x = 2.0f * (vy * pz - vz * py);
        float t1y = 2.0f * (vz * px - vx * pz);
        float t1z = 2.0f * (vx * py - vy * px);
        float plx = px + qw * t1x + (vy * t1z - vz * t1y);
        float ply = py + qw * t1y + (vz * t1x - vx * t1z);
        plzv[p]   = pz + qw * t1z + (vx * t1y - vy * t1x);
        psq[p]    = plx * plx + ply * ply;
        float sx = 4.0f * plx, sy = 4.0f * ply;   // exact pow2 scale
        plx4[p].x = sx; plx4[p].y = sx;
        ply4[p].x = sy; ply4[p].y = sy;
    }

    // 4x-scaled tracking: d4 = 4*(csq - 2*dot) bit-exactly; argmin identical.
    float best4[4] = {1e30f, 1e30f, 1e30f, 1e30f};
    float bcsq4[4] = {0.0f, 0.0f, 0.0f, 0.0f};
    const f32x4* cbase = ((const f32x4*)s_pool) + k;   // [j*64] stride, 1KB imm
    f32x4 cc = cbase[0];
#pragma unroll
    for (int j = 0; j < 32; ++j) {
        f32x4 cn = cbase[(((j + 1) & 31)) * 64];        // prefetch (wraps once)
        f32x2 cx2 = cc.xy, cy2 = cc.zw;
        f32x2 cq2 = pk_fma(cx2, cx2, pk_mul(cy2, cy2)); // = 4*csq bit-exact
#pragma unroll
        for (int p = 0; p < 4; ++p) {
            f32x2 d = pk_fma(cx2, plx4[p], pk_fma(cy2, ply4[p], cq2));
            if (d.x < best4[p]) { best4[p] = d.x; bcsq4[p] = cq2.x; }
            if (d.y < best4[p]) { best4[p] = d.y; bcsq4[p] = cq2.y; }
        }
        cc = cn;
    }

    float occ[4];
#pragma unroll
    for (int p = 0; p < 4; ++p) {
        float d2    = psq[p] + 0.25f * best4[p];        // == psq + best (exact)
        float bq    = 0.25f * bcsq4[p];                 // == bcsq (exact)
        float ud    = sqrtf(fmaxf(d2, 0.0f) + 1e-12f);
        float sgn   = (sqrtf(psq[p]) <= sqrtf(bq)) ? -1.0f : 1.0f;
        float sdf2d = sgn * ud;
        float dzv   = fabsf(plzv[p]) - t4.w;
        float inner = fminf(fmaxf(sdf2d, dzv), 0.0f);
        float r1m   = fmaxf(sdf2d, 0.0f), r2m = fmaxf(dzv, 0.0f);
        float psdf  = inner + sqrtf(r1m * r1m + r2m * r2m + 1e-12f);
        out[OFF_PSDF + (pt0 + p) * Kk + k] = psdf;
        out[OFF_SD   + (pt0 + p) * Kk + k] = ud;
        occ[p] = frcp(1.0f + fexp2(S75 * psdf));   // sigmoid(-75*psdf)
    }

    // ---- barrier: all curve reads done; alias curve region with occ ----
    __syncthreads();
    {
        f32x4 o4; o4.x = occ[0]; o4.y = occ[1]; o4.z = occ[2]; o4.w = occ[3];
        ((f32x4*)s_pool)[tid] = o4;      // same-wave consumers only
    }

    // ================= Phase 2: lane = (khalf, c) =================
    const int training = flag[0];
    const int c    = lane & 31;
    const int kb   = lane & 32;
    const f32x4* occp = ((const f32x4*)s_pool) + (wid << 6) + kb;   // [j]
    const f32x2* iwp  = ((const f32x2*)&s_pool[8192]) + (kb << 5) + c; // [j*32]

    float inter[4];
    if (training) {
        float sw[4]  = {0, 0, 0, 0};
        float swp[4] = {0, 0, 0, 0};
        f32x4 oc = occp[0];
        f32x2 wv = iwp[0];
#pragma unroll
        for (int j = 0; j < 32; ++j) {
            int jn = (j + 1) & 31;
            f32x4 on = occp[jn];
            f32x2 wn = iwp[jn * 32];
            float os[4] = {oc.x, oc.y, oc.z, oc.w};
#pragma unroll
            for (int p = 0; p < 4; ++p) {
                float pre = fmaf(wv.x, os[p], wv.y);   // = -40*log2e * pre_i
                float e   = fexp2(pre);                 // in (0,1]: safe
                sw[p]  += e;
                swp[p]  = fmaf(e, pre, swp[p]);
            }
            oc = on; wv = wn;
        }
#pragma unroll
        for (int p = 0; p < 4; ++p) {
            float swt  = sw[p]  + __shfl_xor(sw[p], 32, 64);
            float swpt = swp[p] + __shfl_xor(swp[p], 32, 64);
            inter[p] = swpt * frcp(swt) * NL2_40;
        }
    } else {
        float mx[4] = {-1e30f, -1e30f, -1e30f, -1e30f};
        f32x4 oc = occp[0];
        f32x2 wv = iwp[0];
#pragma unroll
        for (int j = 0; j < 32; ++j) {
            int jn = (j + 1) & 31;
            f32x4 on = occp[jn];
            f32x2 wn = iwp[jn * 32];
            float os[4] = {oc.x, oc.y, oc.z, oc.w};
#pragma unroll
            for (int p = 0; p < 4; ++p)
                mx[p] = fmaxf(mx[p], fmaf(wv.x, os[p], wv.y));
            oc = on; wv = wn;
        }
#pragma unroll
        for (int p = 0; p < 4; ++p) {
            float m2 = fmaxf(mx[p], __shfl_xor(mx[p], 32, 64));
            inter[p] = m2 * NL2_40;                 // min_k pre_i
        }
    }

    if (lane < Cc) {
#pragma unroll
        for (int p = 0; p < 4; ++p)
            out[OFF_INTER + (pt0 + p) * Cc + c] = inter[p];
    }

    // ---- union over c (softmax / max) ----
    float uwv = uw_g[b * Cc + c];
    float resv[4];
    if (training) {
#pragma unroll
        for (int p = 0; p < 4; ++p) {
            float pu  = uwv * inter[p];
            float e   = fexp2(W40 * pu);            // exp(40*pre_u), <= e^40: safe
            float num = e * pu, den = e;
#pragma unroll
            for (int msk = 16; msk >= 1; msk >>= 1) {
                num += __shfl_xor(num, msk, 64);
                den += __shfl_xor(den, msk, 64);
            }
            resv[p] = num * frcp(den);
        }
    } else {
#pragma unroll
        for (int p = 0; p < 4; ++p) {
            float pu = uwv * inter[p];
#pragma unroll
            for (int msk = 16; msk >= 1; msk >>= 1)
                pu = fmaxf(pu, __shfl_xor(pu, msk, 64));
            resv[p] = pu;
        }
    }
    if (lane == 0)
        *(float4*)(out + pt0) = make_float4(resv[0], resv[1], resv[2], resv[3]);
}

// ---------------- host launch ----------------------------------------------
extern "C" void kernel_launch(void* const* d_in, const int* in_sizes, int n_in,
                              void* d_out, int out_size, void* d_ws, size_t ws_size,
                              hipStream_t stream)
{
    const float* pts  = (const float*)d_in[0];
    const float* pp   = (const float*)d_in[1];
    const float* iw   = (const float*)d_in[2];
    const float* uw   = (const float*)d_in[3];
    const int*   flag = (const int*)d_in[4];
    float* out = (float*)d_out;

    float* ws_c = (float*)d_ws;                        // 128 KB (32768 floats)
    float* params_ws = ws_c + 32768;                   // 8 KB

    // control radians with host libm (matches CPython math module)
    Rad12 rad;
    const double th = M_PI * 2.0 / 16.0 + atan(tan(2.0 * M_PI / 16.0) / 3.0);
    for (int i = 0; i < 4; ++i) {
        double base = 2.0 * M_PI / 4.0 * (double)i;
        rad.v[3 * i + 0] = (float)base;
        rad.v[3 * i + 1] = (float)(base + th);
        rad.v[3 * i + 2] = (float)(2.0 * M_PI / 4.0 * (double)(i + 1) - th);
    }

    curve_prep<<<64, 256, 0, stream>>>(pp, rad, ws_c, params_ws);
    csg_main<<<Bb * Mm / 32, 512, 0, stream>>>(pts, iw, uw, flag,
                                               ws_c, params_ws, out);
}